// Round 4
// baseline (1346.393 us; speedup 1.0000x reference)
//
#include <hip/hip_runtime.h>

// ColumnSelfAttention: R=128, C=256, B=1, E=768, H=12, D=64. **f32 in/out**.
// d_out = [output: TE f32] ++ [probs: 2*TE f32], TE = 32768*768. ZERO d_ws usage.
//
// Slot-interleaved scratch layout inside the output region (bytes [0, 4*TE)):
//   slot t (= output row t) occupies bytes [3072t, 3072t+3072):
//     even half, u16 idx [1536t      , 1536t+ 768): ctx[t][0..768) bf16 (attn writes)
//     odd  half, u16 idx [1536t+ 768 , 1536t+1536): V  [t][0..768) bf16 (QKV-proj writes)
//   gemm_out writes output f32 row t over exactly its own slot:
//     cols [384,768) -> odd half  (dead V)      -> launch 1
//     cols [0,384)   -> even half (own ctx)     -> launch 2 (block reads own ctx
//                                                  in k-loop, writes in epilogue)
//   Pre-attn, even halves of slots [0,4608) hold pre-split projection weights
//   (bf16 hi/lo): wq_hi slots [0,768), wq_lo [768,1536), wk_hi [1536,2304),
//   wk_lo [2304,3072), wv_hi [3072,3840), wv_lo [3840,4608).
//
// gemm_qkv (this round): ONE fused projection GEMM for Q,K,V.
//   Rationale: the 3 separate projections shared A (x) and the whole staging
//   pipeline; each k-iter had only 48 MFMAs (~240cy) vs ~400cy exposed latency
//   (MfmaUtil 18%). Fused: A fetched+split+staged ONCE, 144 MFMAs per k-iter
//   per wave -> 3x compute per unit of staging/barrier/load latency.
//   512 threads (8 waves, 2 row-groups x 4 col-groups), per-wave tile 64x32
//   per matrix; acc[3][4][2] f32x4 = 96 VGPR.
//   Keeps: single-barrier pipelined k-loop (A double-buffered, prefetch before
//   MFMAs, split+write after), XOR-swizzled LDS, XCD-chunked remap (1536=8*192).
//
// MFMA precision: f32 operands split to bf16 hi/lo (truncating split; pair error
// ~2^-16 rel); 3-term (hh+hl+lh) for projections and QK^T; P/V/ctx single-bf16.

typedef __attribute__((ext_vector_type(8))) __bf16 bf16x8;
typedef __attribute__((ext_vector_type(4))) float f32x4;
typedef unsigned short u16;
typedef unsigned int u32;

constexpr size_t TE = (size_t)32768 * 768;
constexpr int VSTRIDE = 256 * 1536;   // u16 stride between V rows j (same c)

__device__ __forceinline__ u16 f2b(float f) {           // RNE, for single-bf16 paths
    u32 u = __builtin_bit_cast(u32, f);
    u += 0x7FFFu + ((u >> 16) & 1u);
    return (u16)(u >> 16);
}
__device__ __forceinline__ void split2(float f, u16& h, u16& l) {  // trunc/trunc
    u32 u = __builtin_bit_cast(u32, f);
    h = (u16)(u >> 16);
    float rest = f - __builtin_bit_cast(float, u & 0xFFFF0000u);
    l = (u16)(__builtin_bit_cast(u32, rest) >> 16);
}

union B8 { bf16x8 v; u16 s[8]; uint4 q; };

// ---------------------------------------------------------------------------
// Pre-split wq/wk/wv (f32) into bf16 hi/lo scratch in slot even-halves.
// ---------------------------------------------------------------------------
__global__ __launch_bounds__(256) void convert_w3(
    const float* __restrict__ Wq, const float* __restrict__ Wk,
    const float* __restrict__ Wv, u16* __restrict__ slots)
{
    const int m = blockIdx.y;
    const float* src = (m == 0) ? Wq : ((m == 1) ? Wk : Wv);
    const int idx = blockIdx.x * 256 + threadIdx.x;   // 0..73727
    const int r = idx / 96, k0 = (idx % 96) * 8;
    float4 f0 = *(const float4*)(src + (size_t)r * 768 + k0);
    float4 f1 = *(const float4*)(src + (size_t)r * 768 + k0 + 4);
    B8 h, l;
    split2(f0.x, h.s[0], l.s[0]); split2(f0.y, h.s[1], l.s[1]);
    split2(f0.z, h.s[2], l.s[2]); split2(f0.w, h.s[3], l.s[3]);
    split2(f1.x, h.s[4], l.s[4]); split2(f1.y, h.s[5], l.s[5]);
    split2(f1.z, h.s[6], l.s[6]); split2(f1.w, h.s[7], l.s[7]);
    *(uint4*)&slots[(size_t)1536 * (m * 1536 + r) + k0] = h.q;         // hi
    *(uint4*)&slots[(size_t)1536 * (m * 1536 + 768 + r) + k0] = l.q;   // lo
}

// ---------------------------------------------------------------------------
// Fused QKV projection GEMM.
// valm[t][n] = (sum_k A[t][k]*Wm[n][k] + biasm[n])*scalem   for m in {Q,K,V}
// M=32768 (t = tm*128+row), N=K=768. 128x128 tile, BK=32, 8 waves (2x4),
// per-wave 64x32 per matrix. A double-buffered in swizzled LDS; B direct from
// pre-split scratch (L2/L3-hot).
// Q (m=0): split2(val*0.125) -> window(h,c)[i*64+d] hi@0 lo@8192
// K (m=1): split2(val)       -> window hi@16384 lo@24576
// V (m=2): f2b(val)          -> slot odd half: slots[t*1536 + 768 + n]
// ---------------------------------------------------------------------------
__global__ __launch_bounds__(512) void gemm_qkv(
    const float* __restrict__ A, const u16* __restrict__ wsl,
    const float* __restrict__ bq, const float* __restrict__ bk,
    const float* __restrict__ bv,
    u16* __restrict__ winU, u16* __restrict__ slots)
{
    // XCD-chunked bijective remap: 1536 = 8 XCDs * 192 blocks.
    const int wg = ((blockIdx.x & 7) * 192) + (blockIdx.x >> 3);
    const int tm = wg / 6, tn = wg - tm * 6;
    const int tid = threadIdx.x;
    const int lane = tid & 63, w = tid >> 6;      // w = 0..7
    const int l16 = lane & 15, quad = lane >> 4;
    const int wr = w >> 2, wc = w & 3;            // 2 row-groups x 4 col-groups

    // [buf][row][col(4, xor-swizzled)][8 u16]; 16 KB + 16 KB
    __shared__ u16 Ah[2][128][4][8], Al[2][128][4][8];

    f32x4 acc[3][4][2];
#pragma unroll
    for (int m = 0; m < 3; ++m)
#pragma unroll
        for (int a = 0; a < 4; ++a)
#pragma unroll
            for (int b = 0; b < 2; ++b) acc[m][a][b] = (f32x4){0.f, 0.f, 0.f, 0.f};

    // Staging geometry: per thread kq fixed, rows row0 and row0+64.
    const int row0 = tid >> 3, kq = tid & 7;
    const int c8 = kq >> 1, o4 = (kq & 1) * 4;
    const float* ap = A + ((size_t)tm * 128 + row0) * 768 + kq * 4;

    float4 pf[2];
#define LOADA(k0) do {                                                        \
    _Pragma("unroll")                                                         \
    for (int it = 0; it < 2; ++it)                                            \
        pf[it] = *(const float4*)(ap + (k0) + (size_t)it * 64 * 768);         \
} while (0)

#define STAGE(buf) do {                                                       \
    _Pragma("unroll")                                                         \
    for (int it = 0; it < 2; ++it) {                                          \
        int row = row0 + 64 * it;                                             \
        int sw = c8 ^ (((row >> 1) ^ (row >> 3)) & 3);                        \
        u16 h0,h1,h2,h3,l0,l1,l2,l3;                                          \
        split2(pf[it].x,h0,l0); split2(pf[it].y,h1,l1);                       \
        split2(pf[it].z,h2,l2); split2(pf[it].w,h3,l3);                       \
        *(uint2*)&Ah[buf][row][sw][o4] =                                      \
            make_uint2((u32)h0|((u32)h1<<16),(u32)h2|((u32)h3<<16));          \
        *(uint2*)&Al[buf][row][sw][o4] =                                      \
            make_uint2((u32)l0|((u32)l1<<16),(u32)l2|((u32)l3<<16));          \
    }                                                                         \
} while (0)

    LOADA(0);
    STAGE(0);
    __syncthreads();

    for (int kc = 0; kc < 24; ++kc) {
        const int buf = kc & 1;
        const int k0 = kc * 32;

        // All B frags (3 matrices) first: vmcnt waits resolve incrementally
        // while the A prefetch stays in flight.
        bf16x8 bh[3][2], bl[3][2];
#pragma unroll
        for (int m = 0; m < 3; ++m)
#pragma unroll
            for (int b = 0; b < 2; ++b) {
                int n = tn * 128 + 32 * wc + 16 * b + l16;
                bh[m][b] = *(const bf16x8*)&wsl[(size_t)1536 * (m * 1536 + n) + k0 + quad * 8];
                bl[m][b] = *(const bf16x8*)&wsl[(size_t)1536 * (m * 1536 + 768 + n) + k0 + quad * 8];
            }
        // Prefetch next A tile (latency hides under the 144-MFMA cluster).
        if (kc < 23) LOADA(k0 + 32);

        bf16x8 ah[4], al[4];
#pragma unroll
        for (int a = 0; a < 4; ++a) {
            int row = 64 * wr + 16 * a + l16;
            int sw = quad ^ (((row >> 1) ^ (row >> 3)) & 3);
            ah[a] = *(const bf16x8*)&Ah[buf][row][sw][0];
            al[a] = *(const bf16x8*)&Al[buf][row][sw][0];
        }
#pragma unroll
        for (int m = 0; m < 3; ++m)
#pragma unroll
            for (int a = 0; a < 4; ++a)
#pragma unroll
                for (int b = 0; b < 2; ++b) {
                    acc[m][a][b] = __builtin_amdgcn_mfma_f32_16x16x32_bf16(ah[a], bh[m][b], acc[m][a][b], 0, 0, 0);
                    acc[m][a][b] = __builtin_amdgcn_mfma_f32_16x16x32_bf16(ah[a], bl[m][b], acc[m][a][b], 0, 0, 0);
                    acc[m][a][b] = __builtin_amdgcn_mfma_f32_16x16x32_bf16(al[a], bh[m][b], acc[m][a][b], 0, 0, 0);
                }
        // Split+write the prefetched tile into the other buffer.
        if (kc < 23) STAGE(buf ^ 1);
        __syncthreads();
    }
#undef LOADA
#undef STAGE

    // C/D layout: col = lane&15, row = quad*4 + reg.
    const float* biases[3] = {bq, bk, bv};
#pragma unroll
    for (int m = 0; m < 3; ++m) {
        const float scale = (m == 0) ? 0.125f : 1.0f;
#pragma unroll
        for (int b = 0; b < 2; ++b) {
            int n = tn * 128 + 32 * wc + 16 * b + l16;
            float bs = biases[m][n];
#pragma unroll
            for (int a = 0; a < 4; ++a) {
#pragma unroll
                for (int r = 0; r < 4; ++r) {
                    int row = 64 * wr + 16 * a + quad * 4 + r;
                    int t = tm * 128 + row;
                    float val = (acc[m][a][b][r] + bs) * scale;
                    if (m == 2) {
                        slots[(size_t)t * 1536 + 768 + n] = f2b(val);   // odd half: V
                    } else {
                        int i = t >> 8, cc = t & 255;
                        int hh = n >> 6, d = n & 63;
                        u16* win = winU + (((size_t)hh * 256 + cc) << 15);
                        int base = (m == 0 ? 0 : 16384);
                        u16 vh, vl; split2(val, vh, vl);
                        win[base + i * 64 + d] = vh;
                        win[base + 8192 + i * 64 + d] = vl;
                    }
                }
            }
        }
    }
}

// ---------------------------------------------------------------------------
// Fused attention per (h,c). Window: Qhi/Qlo/Khi/Klo in -> probs (f32) out.
// V bf16 from slot odd halves; ctx bf16 to slot even halves.
// ---------------------------------------------------------------------------
__global__ __launch_bounds__(256) void attn_kernel(
    u16* __restrict__ winU,            // probs region as u16
    u16* __restrict__ slots,           // V reads (odd half), ctx writes (even half)
    const int* __restrict__ maskg)
{
    const int blk = blockIdx.x;
    const int c = blk & 255, h = blk >> 8;
    const int tid = threadIdx.x;
    const int lane = tid & 63, w = tid >> 6;
    const int l16 = lane & 15, quad = lane >> 4;

    __shared__ u16 kbuf[2][8][128][8];   // Khi, Klo (32 KB); ps overlays both
    __shared__ u16 vsT[16][64][8];       // V transposed, chunked (16 KB)
    u16 (*ps)[128][8] = (u16(*)[128][8])&kbuf[0][0][0][0];

    u16* win = winU + (((size_t)h * 256 + c) << 15);
    float* winF = (float*)win;

    // Stage K hi/lo (contiguous window rows) and V (transposed).
#pragma unroll
    for (int it = 0; it < 4; ++it) {
        int v = tid + 256 * it;          // 0..1023
        int j = v >> 3, d0 = (v & 7) * 8;
        *(uint4*)&kbuf[0][d0 >> 3][j][0] = *(const uint4*)(win + 16384 + j * 64 + d0);
        *(uint4*)&kbuf[1][d0 >> 3][j][0] = *(const uint4*)(win + 24576 + j * 64 + d0);
    }
    const u16* vb = slots + (size_t)c * 1536 + 768 + h * 64;   // V odd half
#pragma unroll
    for (int it = 0; it < 4; ++it) {
        int v = tid + 256 * it;
        int j = v >> 3, d0 = (v & 7) * 8;
        B8 t; t.q = *(const uint4*)(vb + (size_t)j * VSTRIDE + d0);
#pragma unroll
        for (int e = 0; e < 8; ++e) vsT[j >> 3][d0 + e][j & 7] = t.s[e];
    }
    __syncthreads();

    // S = Q K^T (Q pre-scaled by 0.125); Q frags straight from own window.
    f32x4 s[2][8];
#pragma unroll
    for (int a = 0; a < 2; ++a)
#pragma unroll
        for (int jb = 0; jb < 8; ++jb) s[a][jb] = (f32x4){0.f, 0.f, 0.f, 0.f};

#pragma unroll
    for (int kc = 0; kc < 2; ++kc) {
        bf16x8 qh[2], ql[2];
#pragma unroll
        for (int a = 0; a < 2; ++a) {
            int i = 32 * w + 16 * a + l16;
            qh[a] = *(const bf16x8*)(win + i * 64 + kc * 32 + quad * 8);
            ql[a] = *(const bf16x8*)(win + 8192 + i * 64 + kc * 32 + quad * 8);
        }
#pragma unroll
        for (int jb = 0; jb < 8; ++jb) {
            bf16x8 kh = *(const bf16x8*)&kbuf[0][kc * 4 + quad][16 * jb + l16][0];
            bf16x8 kl = *(const bf16x8*)&kbuf[1][kc * 4 + quad][16 * jb + l16][0];
#pragma unroll
            for (int a = 0; a < 2; ++a) {
                s[a][jb] = __builtin_amdgcn_mfma_f32_16x16x32_bf16(qh[a], kh, s[a][jb], 0, 0, 0);
                s[a][jb] = __builtin_amdgcn_mfma_f32_16x16x32_bf16(qh[a], kl, s[a][jb], 0, 0, 0);
                s[a][jb] = __builtin_amdgcn_mfma_f32_16x16x32_bf16(ql[a], kh, s[a][jb], 0, 0, 0);
            }
        }
    }

    // Masked column: all scores -10000 -> uniform softmax == softmax(0).
    if (maskg[c] != 0) {
#pragma unroll
        for (int a = 0; a < 2; ++a)
#pragma unroll
            for (int jb = 0; jb < 8; ++jb) s[a][jb] = (f32x4){0.f, 0.f, 0.f, 0.f};
    }

    // Row softmax in place (row (a,quad,r) spans the 16 lanes of this quad).
#pragma unroll
    for (int a = 0; a < 2; ++a) {
#pragma unroll
        for (int r = 0; r < 4; ++r) {
            float m = s[a][0][r];
#pragma unroll
            for (int jb = 1; jb < 8; ++jb) m = fmaxf(m, s[a][jb][r]);
#pragma unroll
            for (int off = 1; off < 16; off <<= 1) m = fmaxf(m, __shfl_xor(m, off, 64));
            float sum = 0.f;
#pragma unroll
            for (int jb = 0; jb < 8; ++jb) {
                float e = expf(s[a][jb][r] - m);
                s[a][jb][r] = e;
                sum += e;
            }
#pragma unroll
            for (int off = 1; off < 16; off <<= 1) sum += __shfl_xor(sum, off, 64);
            float inv = 1.f / sum;
#pragma unroll
            for (int jb = 0; jb < 8; ++jb) s[a][jb][r] *= inv;
        }
    }

    // Barrier: all waves' Q global reads + K LDS reads are retired (consumed
    // by MFMAs) before we overwrite the window (probs) and kbuf (ps).
    __syncthreads();

#pragma unroll
    for (int a = 0; a < 2; ++a)
#pragma unroll
        for (int jb = 0; jb < 8; ++jb)
#pragma unroll
            for (int r = 0; r < 4; ++r) {
                int i = 32 * w + 16 * a + quad * 4 + r;
                int j = 16 * jb + l16;
                float pv = s[a][jb][r];
                winF[i * 128 + j] = pv;                 // probs, f32, final layout
                ps[j >> 3][i][j & 7] = f2b(pv);         // A-operand for PV
            }
    __syncthreads();

    // PV: ctx[i][d] = sum_j P[i][j] V[j][d]
    f32x4 o[2][4];
#pragma unroll
    for (int a = 0; a < 2; ++a)
#pragma unroll
        for (int b = 0; b < 4; ++b) o[a][b] = (f32x4){0.f, 0.f, 0.f, 0.f};

#pragma unroll
    for (int kc = 0; kc < 4; ++kc) {
        bf16x8 ap[2];
#pragma unroll
        for (int a = 0; a < 2; ++a)
            ap[a] = *(const bf16x8*)&ps[kc * 4 + quad][32 * w + 16 * a + l16][0];
#pragma unroll
        for (int b = 0; b < 4; ++b) {
            bf16x8 bv = *(const bf16x8*)&vsT[kc * 4 + quad][16 * b + l16][0];
#pragma unroll
            for (int a = 0; a < 2; ++a)
                o[a][b] = __builtin_amdgcn_mfma_f32_16x16x32_bf16(ap[a], bv, o[a][b], 0, 0, 0);
        }
    }

    // ctx (bf16) -> own slot even halves, this block's own (c,h) token slice.
#pragma unroll
    for (int a = 0; a < 2; ++a)
#pragma unroll
        for (int b = 0; b < 4; ++b)
#pragma unroll
            for (int r = 0; r < 4; ++r) {
                int i = 32 * w + 16 * a + quad * 4 + r;
                int d = 16 * b + l16;
                slots[(size_t)(i * 256 + c) * 1536 + h * 64 + d] = f2b(o[a][b][r]);
            }
}

// ---------------------------------------------------------------------------
// Final GEMM: out[t][n] = sum_k ctx[t][k]*wo[n][k] + bo[n], n in [nb, nb+384).
// 64-row blocks, 4 waves (96 cols each), ctx double-buffered in LDS (8 KB),
// W f32 read per-lane from L2 and split on the fly (amortized over 64 rows).
// Launch 1: nb=384 (writes odd halves = dead V). Launch 2: nb=0 (writes even
// halves = own ctx, after this block's k-loop reads). MUST run in this order.
// ---------------------------------------------------------------------------
__global__ __launch_bounds__(256) void gemm_out(
    const u16* __restrict__ slots, const float* __restrict__ W,
    const float* __restrict__ bias, float* __restrict__ out0, int nb)
{
    const int t0 = blockIdx.x * 64;
    const int tid = threadIdx.x;
    const int lane = tid & 63, w = tid >> 6;
    const int l16 = lane & 15, quad = lane >> 4;

    __shared__ u16 cs[2][4][64][8];   // [buf][k8][row][8] = 8 KB

    f32x4 acc[4][6];
#pragma unroll
    for (int a = 0; a < 4; ++a)
#pragma unroll
        for (int jt = 0; jt < 6; ++jt) acc[a][jt] = (f32x4){0.f, 0.f, 0.f, 0.f};

    const int srow = tid >> 2, sk8 = tid & 3;           // 64 rows x 4 k-octets
    const u16* sp = slots + (size_t)(t0 + srow) * 1536 + sk8 * 8;   // ctx even half

    *(uint4*)&cs[0][sk8][srow][0] = *(const uint4*)(sp);
    for (int kc = 0; kc < 24; ++kc) {
        const int buf = kc & 1;
        __syncthreads();
        if (kc + 1 < 24)
            *(uint4*)&cs[buf ^ 1][sk8][srow][0] = *(const uint4*)(sp + (kc + 1) * 32);

        bf16x8 af[4];
#pragma unroll
        for (int a = 0; a < 4; ++a)
            af[a] = *(const bf16x8*)&cs[buf][quad][16 * a + l16][0];

#pragma unroll
        for (int jt = 0; jt < 6; ++jt) {
            int n = nb + 96 * w + 16 * jt + l16;
            const float* wp = W + (size_t)n * 768 + kc * 32 + quad * 8;
            float4 f0 = *(const float4*)(wp);
            float4 f1 = *(const float4*)(wp + 4);
            B8 wh, wl;
            split2(f0.x, wh.s[0], wl.s[0]); split2(f0.y, wh.s[1], wl.s[1]);
            split2(f0.z, wh.s[2], wl.s[2]); split2(f0.w, wh.s[3], wl.s[3]);
            split2(f1.x, wh.s[4], wl.s[4]); split2(f1.y, wh.s[5], wl.s[5]);
            split2(f1.z, wh.s[6], wl.s[6]); split2(f1.w, wh.s[7], wl.s[7]);
#pragma unroll
            for (int a = 0; a < 4; ++a) {
                acc[a][jt] = __builtin_amdgcn_mfma_f32_16x16x32_bf16(af[a], wh.v, acc[a][jt], 0, 0, 0);
                acc[a][jt] = __builtin_amdgcn_mfma_f32_16x16x32_bf16(af[a], wl.v, acc[a][jt], 0, 0, 0);
            }
        }
    }

    // C/D layout: col = lane&15, row = quad*4 + reg.
#pragma unroll
    for (int jt = 0; jt < 6; ++jt) {
        int n = nb + 96 * w + 16 * jt + l16;
        float bs = bias[n];
#pragma unroll
        for (int a = 0; a < 4; ++a) {
#pragma unroll
            for (int r = 0; r < 4; ++r) {
                int row = 16 * a + quad * 4 + r;
                out0[(size_t)(t0 + row) * 768 + n] = acc[a][jt][r] + bs;
            }
        }
    }
}

// ---------------------------------------------------------------------------
extern "C" void kernel_launch(void* const* d_in, const int* in_sizes, int n_in,
                              void* d_out, int out_size, void* d_ws, size_t ws_size,
                              hipStream_t stream) {
    const float* x    = (const float*)d_in[0];
    const int*   mask = (const int*)d_in[1];
    const float* wq = (const float*)d_in[2];
    const float* bq = (const float*)d_in[3];
    const float* wk = (const float*)d_in[4];
    const float* bk = (const float*)d_in[5];
    const float* wv = (const float*)d_in[6];
    const float* bv = (const float*)d_in[7];
    const float* wo = (const float*)d_in[8];
    const float* bo = (const float*)d_in[9];

    float* out0  = (float*)d_out;                // TE f32 (slot-interleaved scratch)
    u16*   slots = (u16*)d_out;                  // ctx even halves, V odd halves
    u16*   winU  = (u16*)(out0 + TE);            // probs region: windows -> probs

    // W pre-split scratch in even halves of slots [0,4608) (dead until attn).
    convert_w3<<<dim3(288, 3), dim3(256), 0, stream>>>(wq, wk, wv, slots);
    // Fused Q,K,V projection (A staged once, 144 MFMAs per k-iter).
    gemm_qkv<<<dim3(1536), dim3(512), 0, stream>>>(x, slots, bq, bk, bv, winU, slots);
    attn_kernel<<<dim3(12 * 256), dim3(256), 0, stream>>>(winU, slots, mask);
    // Order matters: cols [384,768) first (odd halves, dead V), then [0,384)
    // (even halves = each block's own, already-read ctx).
    gemm_out<<<dim3(512), dim3(256), 0, stream>>>(slots, wo, bo, out0, 384);
    gemm_out<<<dim3(512), dim3(256), 0, stream>>>(slots, wo, bo, out0, 0);
}

// Round 5
// 1172.186 us; speedup vs baseline: 1.1486x; 1.1486x over previous
//
#include <hip/hip_runtime.h>

// ColumnSelfAttention: R=128, C=256, B=1, E=768, H=12, D=64. **f32 in/out**.
// d_out = [output: TE f32] ++ [probs: 2*TE f32], TE = 32768*768. ZERO d_ws usage.
//
// Slot-interleaved scratch layout inside the output region (bytes [0, 4*TE)):
//   slot t (= output row t) occupies bytes [3072t, 3072t+3072):
//     even half, u16 idx [1536t      , 1536t+ 768): ctx[t][0..768) bf16 (attn writes)
//     odd  half, u16 idx [1536t+ 768 , 1536t+1536): V  [t][0..768) bf16 (QKV-proj writes)
//   gemm_out writes output f32 row t over exactly its own slot:
//     cols [384,768) -> odd half  (dead V)      -> launch 1
//     cols [0,384)   -> even half (own ctx)     -> launch 2 (block reads own ctx
//                                                  in k-loop, writes in epilogue)
//
//   Pre-attn, even halves of slots [0,6912) hold the pre-split projection
//   weights in MFMA-FRAGMENT-READY 1KB chunks (this round's change):
//     chunk(kb,nb,m,half), id = (kb*48+nb)*6 + m*2 + half, kb in [0,24),
//     nb in [0,48), m in {Q,K,V}, half in {hi,lo};
//     chunk base u16 = 1536*id (even half of slot id, first 512 of 768 u16);
//     element (l16, quad, e) at offset l16*32 + quad*8 + e
//       = Wm[nb*16 + l16][kb*32 + quad*8 + e]  (bf16 hi/lo of f32 split).
//   => a wave's B-fragment load is ONE coalesced 1KB read (was a 16-line
//      3072B-stride gather = 4x L2 over-read + exposed gather latency);
//      the 12 chunks a wave needs per k-iter are CONTIGUOUS 12KB; per-GPU
//      working set per kb-step is 288KB -> L2-resident on every XCD.
//   attn's ctx writes later overwrite the chunks (dead by then); V writes
//   touch only odd halves -> no collision.
//
// gemm_qkv: ONE fused projection GEMM for Q,K,V (A fetched+split+staged once,
//   144 MFMA-equiv per k-iter). 512 threads (8 waves, 2 row x 4 col groups),
//   per-wave tile 64x32 per matrix; acc[3][4][2] f32x4 = 96 acc regs.
//   Single-barrier pipelined k-loop (A double-buffered in XOR-swizzled LDS,
//   prefetch before MFMAs, split+write after), XCD-chunked remap (1536=8*192).
//
// MFMA precision: f32 operands split to bf16 hi/lo (truncating split; pair error
// ~2^-16 rel); 3-term (hh+hl+lh) for projections and QK^T; P/V/ctx single-bf16.

typedef __attribute__((ext_vector_type(8))) __bf16 bf16x8;
typedef __attribute__((ext_vector_type(4))) float f32x4;
typedef unsigned short u16;
typedef unsigned int u32;

constexpr size_t TE = (size_t)32768 * 768;
constexpr int VSTRIDE = 256 * 1536;   // u16 stride between V rows j (same c)

__device__ __forceinline__ u16 f2b(float f) {           // RNE, for single-bf16 paths
    u32 u = __builtin_bit_cast(u32, f);
    u += 0x7FFFu + ((u >> 16) & 1u);
    return (u16)(u >> 16);
}
__device__ __forceinline__ void split2(float f, u16& h, u16& l) {  // trunc/trunc
    u32 u = __builtin_bit_cast(u32, f);
    h = (u16)(u >> 16);
    float rest = f - __builtin_bit_cast(float, u & 0xFFFF0000u);
    l = (u16)(__builtin_bit_cast(u32, rest) >> 16);
}

union B8 { bf16x8 v; u16 s[8]; uint4 q; };

// ---------------------------------------------------------------------------
// Pre-split wq/wk/wv (f32) into fragment-ready bf16 hi/lo chunks (see header).
// grid (288, 3): blockIdx.y = matrix m; 288*256 threads = 73728 = 768*96.
// Thread handles one (row r, k-octet oct): 8 elements -> one 16B write per half.
// ---------------------------------------------------------------------------
__global__ __launch_bounds__(256) void convert_w3(
    const float* __restrict__ Wq, const float* __restrict__ Wk,
    const float* __restrict__ Wv, u16* __restrict__ slots)
{
    const int m = blockIdx.y;
    const float* src = (m == 0) ? Wq : ((m == 1) ? Wk : Wv);
    const int idx = blockIdx.x * 256 + threadIdx.x;   // 0..73727
    const int r = idx / 96, oct = idx % 96;           // r = n-row, oct = k/8
    const int nb = r >> 4, i = r & 15;
    const int kb = oct >> 2, quad = oct & 3;
    float4 f0 = *(const float4*)(src + (size_t)r * 768 + oct * 8);
    float4 f1 = *(const float4*)(src + (size_t)r * 768 + oct * 8 + 4);
    B8 h, l;
    split2(f0.x, h.s[0], l.s[0]); split2(f0.y, h.s[1], l.s[1]);
    split2(f0.z, h.s[2], l.s[2]); split2(f0.w, h.s[3], l.s[3]);
    split2(f1.x, h.s[4], l.s[4]); split2(f1.y, h.s[5], l.s[5]);
    split2(f1.z, h.s[6], l.s[6]); split2(f1.w, h.s[7], l.s[7]);
    const size_t cid = (size_t)((kb * 48 + nb) * 6 + m * 2);
    const int off = i * 32 + quad * 8;
    *(uint4*)&slots[cid * 1536 + off] = h.q;            // hi chunk
    *(uint4*)&slots[(cid + 1) * 1536 + off] = l.q;      // lo chunk
}

// ---------------------------------------------------------------------------
// Fused QKV projection GEMM.
// valm[t][n] = (sum_k A[t][k]*Wm[n][k] + biasm[n])*scalem   for m in {Q,K,V}
// M=32768 (t = tm*128+row), N=K=768. 128x128 tile, BK=32, 8 waves (2x4),
// per-wave 64x32 per matrix. A double-buffered in swizzled LDS; B read as
// coalesced fragment chunks from pre-split scratch (L2-hot).
// Q (m=0): split2(val*0.125) -> window(h,c)[i*64+d] hi@0 lo@8192
// K (m=1): split2(val)       -> window hi@16384 lo@24576
// V (m=2): f2b(val)          -> slot odd half: slots[t*1536 + 768 + n]
// ---------------------------------------------------------------------------
__global__ __launch_bounds__(512) void gemm_qkv(
    const float* __restrict__ A, const u16* __restrict__ wsl,
    const float* __restrict__ bq, const float* __restrict__ bk,
    const float* __restrict__ bv,
    u16* __restrict__ winU, u16* __restrict__ slots)
{
    // XCD-chunked bijective remap: 1536 = 8 XCDs * 192 blocks.
    const int wg = ((blockIdx.x & 7) * 192) + (blockIdx.x >> 3);
    const int tm = wg / 6, tn = wg - tm * 6;
    const int tid = threadIdx.x;
    const int lane = tid & 63, w = tid >> 6;      // w = 0..7
    const int l16 = lane & 15, quad = lane >> 4;
    const int wr = w >> 2, wc = w & 3;            // 2 row-groups x 4 col-groups

    // [buf][row][col(4, xor-swizzled)][8 u16]; 16 KB + 16 KB
    __shared__ u16 Ah[2][128][4][8], Al[2][128][4][8];

    f32x4 acc[3][4][2];
#pragma unroll
    for (int m = 0; m < 3; ++m)
#pragma unroll
        for (int a = 0; a < 4; ++a)
#pragma unroll
            for (int b = 0; b < 2; ++b) acc[m][a][b] = (f32x4){0.f, 0.f, 0.f, 0.f};

    // Staging geometry: per thread kq fixed, rows row0 and row0+64.
    const int row0 = tid >> 3, kq = tid & 7;
    const int c8 = kq >> 1, o4 = (kq & 1) * 4;
    const float* ap = A + ((size_t)tm * 128 + row0) * 768 + kq * 4;

    // B chunk addressing: lane-linear offset within each 1KB chunk.
    const int coff = l16 * 32 + quad * 8;

    float4 pf[2];
#define LOADA(k0) do {                                                        \
    _Pragma("unroll")                                                         \
    for (int it = 0; it < 2; ++it)                                            \
        pf[it] = *(const float4*)(ap + (k0) + (size_t)it * 64 * 768);         \
} while (0)

#define STAGE(buf) do {                                                       \
    _Pragma("unroll")                                                         \
    for (int it = 0; it < 2; ++it) {                                          \
        int row = row0 + 64 * it;                                             \
        int sw = c8 ^ (((row >> 1) ^ (row >> 3)) & 3);                        \
        u16 h0,h1,h2,h3,l0,l1,l2,l3;                                          \
        split2(pf[it].x,h0,l0); split2(pf[it].y,h1,l1);                       \
        split2(pf[it].z,h2,l2); split2(pf[it].w,h3,l3);                       \
        *(uint2*)&Ah[buf][row][sw][o4] =                                      \
            make_uint2((u32)h0|((u32)h1<<16),(u32)h2|((u32)h3<<16));          \
        *(uint2*)&Al[buf][row][sw][o4] =                                      \
            make_uint2((u32)l0|((u32)l1<<16),(u32)l2|((u32)l3<<16));          \
    }                                                                         \
} while (0)

    LOADA(0);
    STAGE(0);
    __syncthreads();

    for (int kc = 0; kc < 24; ++kc) {
        const int buf = kc & 1;
        const int k0 = kc * 32;

        // B frags: coalesced 1KB chunk reads, m-major so the compiler can
        // wait vmcnt incrementally (m=0 MFMAs start while m=1,2 in flight).
        bf16x8 bh[3][2], bl[3][2];
#pragma unroll
        for (int m = 0; m < 3; ++m)
#pragma unroll
            for (int b = 0; b < 2; ++b) {
                int nbg = tn * 8 + wc * 2 + b;
                size_t cb = (size_t)1536 * (size_t)((kc * 48 + nbg) * 6 + m * 2);
                bh[m][b] = *(const bf16x8*)&wsl[cb + coff];
                bl[m][b] = *(const bf16x8*)&wsl[cb + 1536 + coff];
            }
        // Prefetch next A tile (latency hides under the MFMA cluster).
        if (kc < 23) LOADA(k0 + 32);

        bf16x8 ah[4], al[4];
#pragma unroll
        for (int a = 0; a < 4; ++a) {
            int row = 64 * wr + 16 * a + l16;
            int sw = quad ^ (((row >> 1) ^ (row >> 3)) & 3);
            ah[a] = *(const bf16x8*)&Ah[buf][row][sw][0];
            al[a] = *(const bf16x8*)&Al[buf][row][sw][0];
        }
#pragma unroll
        for (int m = 0; m < 3; ++m)
#pragma unroll
            for (int a = 0; a < 4; ++a)
#pragma unroll
                for (int b = 0; b < 2; ++b) {
                    acc[m][a][b] = __builtin_amdgcn_mfma_f32_16x16x32_bf16(ah[a], bh[m][b], acc[m][a][b], 0, 0, 0);
                    acc[m][a][b] = __builtin_amdgcn_mfma_f32_16x16x32_bf16(ah[a], bl[m][b], acc[m][a][b], 0, 0, 0);
                    acc[m][a][b] = __builtin_amdgcn_mfma_f32_16x16x32_bf16(al[a], bh[m][b], acc[m][a][b], 0, 0, 0);
                }
        // Split+write the prefetched tile into the other buffer.
        if (kc < 23) STAGE(buf ^ 1);
        __syncthreads();
    }
#undef LOADA
#undef STAGE

    // C/D layout: col = lane&15, row = quad*4 + reg.
    const float* biases[3] = {bq, bk, bv};
#pragma unroll
    for (int m = 0; m < 3; ++m) {
        const float scale = (m == 0) ? 0.125f : 1.0f;
#pragma unroll
        for (int b = 0; b < 2; ++b) {
            int n = tn * 128 + 32 * wc + 16 * b + l16;
            float bs = biases[m][n];
#pragma unroll
            for (int a = 0; a < 4; ++a) {
#pragma unroll
                for (int r = 0; r < 4; ++r) {
                    int row = 64 * wr + 16 * a + quad * 4 + r;
                    int t = tm * 128 + row;
                    float val = (acc[m][a][b][r] + bs) * scale;
                    if (m == 2) {
                        slots[(size_t)t * 1536 + 768 + n] = f2b(val);   // odd half: V
                    } else {
                        int i = t >> 8, cc = t & 255;
                        int hh = n >> 6, d = n & 63;
                        u16* win = winU + (((size_t)hh * 256 + cc) << 15);
                        int base = (m == 0 ? 0 : 16384);
                        u16 vh, vl; split2(val, vh, vl);
                        win[base + i * 64 + d] = vh;
                        win[base + 8192 + i * 64 + d] = vl;
                    }
                }
            }
        }
    }
}

// ---------------------------------------------------------------------------
// Fused attention per (h,c). Window: Qhi/Qlo/Khi/Klo in -> probs (f32) out.
// V bf16 from slot odd halves; ctx bf16 to slot even halves.
// ---------------------------------------------------------------------------
__global__ __launch_bounds__(256) void attn_kernel(
    u16* __restrict__ winU,            // probs region as u16
    u16* __restrict__ slots,           // V reads (odd half), ctx writes (even half)
    const int* __restrict__ maskg)
{
    const int blk = blockIdx.x;
    const int c = blk & 255, h = blk >> 8;
    const int tid = threadIdx.x;
    const int lane = tid & 63, w = tid >> 6;
    const int l16 = lane & 15, quad = lane >> 4;

    __shared__ u16 kbuf[2][8][128][8];   // Khi, Klo (32 KB); ps overlays both
    __shared__ u16 vsT[16][64][8];       // V transposed, chunked (16 KB)
    u16 (*ps)[128][8] = (u16(*)[128][8])&kbuf[0][0][0][0];

    u16* win = winU + (((size_t)h * 256 + c) << 15);
    float* winF = (float*)win;

    // Stage K hi/lo (contiguous window rows) and V (transposed).
#pragma unroll
    for (int it = 0; it < 4; ++it) {
        int v = tid + 256 * it;          // 0..1023
        int j = v >> 3, d0 = (v & 7) * 8;
        *(uint4*)&kbuf[0][d0 >> 3][j][0] = *(const uint4*)(win + 16384 + j * 64 + d0);
        *(uint4*)&kbuf[1][d0 >> 3][j][0] = *(const uint4*)(win + 24576 + j * 64 + d0);
    }
    const u16* vb = slots + (size_t)c * 1536 + 768 + h * 64;   // V odd half
#pragma unroll
    for (int it = 0; it < 4; ++it) {
        int v = tid + 256 * it;
        int j = v >> 3, d0 = (v & 7) * 8;
        B8 t; t.q = *(const uint4*)(vb + (size_t)j * VSTRIDE + d0);
#pragma unroll
        for (int e = 0; e < 8; ++e) vsT[j >> 3][d0 + e][j & 7] = t.s[e];
    }
    __syncthreads();

    // S = Q K^T (Q pre-scaled by 0.125); Q frags straight from own window.
    f32x4 s[2][8];
#pragma unroll
    for (int a = 0; a < 2; ++a)
#pragma unroll
        for (int jb = 0; jb < 8; ++jb) s[a][jb] = (f32x4){0.f, 0.f, 0.f, 0.f};

#pragma unroll
    for (int kc = 0; kc < 2; ++kc) {
        bf16x8 qh[2], ql[2];
#pragma unroll
        for (int a = 0; a < 2; ++a) {
            int i = 32 * w + 16 * a + l16;
            qh[a] = *(const bf16x8*)(win + i * 64 + kc * 32 + quad * 8);
            ql[a] = *(const bf16x8*)(win + 8192 + i * 64 + kc * 32 + quad * 8);
        }
#pragma unroll
        for (int jb = 0; jb < 8; ++jb) {
            bf16x8 kh = *(const bf16x8*)&kbuf[0][kc * 4 + quad][16 * jb + l16][0];
            bf16x8 kl = *(const bf16x8*)&kbuf[1][kc * 4 + quad][16 * jb + l16][0];
#pragma unroll
            for (int a = 0; a < 2; ++a) {
                s[a][jb] = __builtin_amdgcn_mfma_f32_16x16x32_bf16(qh[a], kh, s[a][jb], 0, 0, 0);
                s[a][jb] = __builtin_amdgcn_mfma_f32_16x16x32_bf16(qh[a], kl, s[a][jb], 0, 0, 0);
                s[a][jb] = __builtin_amdgcn_mfma_f32_16x16x32_bf16(ql[a], kh, s[a][jb], 0, 0, 0);
            }
        }
    }

    // Masked column: all scores -10000 -> uniform softmax == softmax(0).
    if (maskg[c] != 0) {
#pragma unroll
        for (int a = 0; a < 2; ++a)
#pragma unroll
            for (int jb = 0; jb < 8; ++jb) s[a][jb] = (f32x4){0.f, 0.f, 0.f, 0.f};
    }

    // Row softmax in place (row (a,quad,r) spans the 16 lanes of this quad).
#pragma unroll
    for (int a = 0; a < 2; ++a) {
#pragma unroll
        for (int r = 0; r < 4; ++r) {
            float m = s[a][0][r];
#pragma unroll
            for (int jb = 1; jb < 8; ++jb) m = fmaxf(m, s[a][jb][r]);
#pragma unroll
            for (int off = 1; off < 16; off <<= 1) m = fmaxf(m, __shfl_xor(m, off, 64));
            float sum = 0.f;
#pragma unroll
            for (int jb = 0; jb < 8; ++jb) {
                float e = expf(s[a][jb][r] - m);
                s[a][jb][r] = e;
                sum += e;
            }
#pragma unroll
            for (int off = 1; off < 16; off <<= 1) sum += __shfl_xor(sum, off, 64);
            float inv = 1.f / sum;
#pragma unroll
            for (int jb = 0; jb < 8; ++jb) s[a][jb][r] *= inv;
        }
    }

    // Barrier: all waves' Q global reads + K LDS reads are retired (consumed
    // by MFMAs) before we overwrite the window (probs) and kbuf (ps).
    __syncthreads();

#pragma unroll
    for (int a = 0; a < 2; ++a)
#pragma unroll
        for (int jb = 0; jb < 8; ++jb)
#pragma unroll
            for (int r = 0; r < 4; ++r) {
                int i = 32 * w + 16 * a + quad * 4 + r;
                int j = 16 * jb + l16;
                float pv = s[a][jb][r];
                winF[i * 128 + j] = pv;                 // probs, f32, final layout
                ps[j >> 3][i][j & 7] = f2b(pv);         // A-operand for PV
            }
    __syncthreads();

    // PV: ctx[i][d] = sum_j P[i][j] V[j][d]
    f32x4 o[2][4];
#pragma unroll
    for (int a = 0; a < 2; ++a)
#pragma unroll
        for (int b = 0; b < 4; ++b) o[a][b] = (f32x4){0.f, 0.f, 0.f, 0.f};

#pragma unroll
    for (int kc = 0; kc < 4; ++kc) {
        bf16x8 ap[2];
#pragma unroll
        for (int a = 0; a < 2; ++a)
            ap[a] = *(const bf16x8*)&ps[kc * 4 + quad][32 * w + 16 * a + l16][0];
#pragma unroll
        for (int b = 0; b < 4; ++b) {
            bf16x8 bv = *(const bf16x8*)&vsT[kc * 4 + quad][16 * b + l16][0];
#pragma unroll
            for (int a = 0; a < 2; ++a)
                o[a][b] = __builtin_amdgcn_mfma_f32_16x16x32_bf16(ap[a], bv, o[a][b], 0, 0, 0);
        }
    }

    // ctx (bf16) -> own slot even halves, this block's own (c,h) token slice.
#pragma unroll
    for (int a = 0; a < 2; ++a)
#pragma unroll
        for (int b = 0; b < 4; ++b)
#pragma unroll
            for (int r = 0; r < 4; ++r) {
                int i = 32 * w + 16 * a + quad * 4 + r;
                int d = 16 * b + l16;
                slots[(size_t)(i * 256 + c) * 1536 + h * 64 + d] = f2b(o[a][b][r]);
            }
}

// ---------------------------------------------------------------------------
// Final GEMM: out[t][n] = sum_k ctx[t][k]*wo[n][k] + bo[n], n in [nb, nb+384).
// 64-row blocks, 4 waves (96 cols each), ctx double-buffered in LDS (8 KB),
// W f32 read per-lane from L2 and split on the fly (amortized over 64 rows).
// Launch 1: nb=384 (writes odd halves = dead V). Launch 2: nb=0 (writes even
// halves = own ctx, after this block's k-loop reads). MUST run in this order.
// ---------------------------------------------------------------------------
__global__ __launch_bounds__(256) void gemm_out(
    const u16* __restrict__ slots, const float* __restrict__ W,
    const float* __restrict__ bias, float* __restrict__ out0, int nb)
{
    const int t0 = blockIdx.x * 64;
    const int tid = threadIdx.x;
    const int lane = tid & 63, w = tid >> 6;
    const int l16 = lane & 15, quad = lane >> 4;

    __shared__ u16 cs[2][4][64][8];   // [buf][k8][row][8] = 8 KB

    f32x4 acc[4][6];
#pragma unroll
    for (int a = 0; a < 4; ++a)
#pragma unroll
        for (int jt = 0; jt < 6; ++jt) acc[a][jt] = (f32x4){0.f, 0.f, 0.f, 0.f};

    const int srow = tid >> 2, sk8 = tid & 3;           // 64 rows x 4 k-octets
    const u16* sp = slots + (size_t)(t0 + srow) * 1536 + sk8 * 8;   // ctx even half

    *(uint4*)&cs[0][sk8][srow][0] = *(const uint4*)(sp);
    for (int kc = 0; kc < 24; ++kc) {
        const int buf = kc & 1;
        __syncthreads();
        if (kc + 1 < 24)
            *(uint4*)&cs[buf ^ 1][sk8][srow][0] = *(const uint4*)(sp + (kc + 1) * 32);

        bf16x8 af[4];
#pragma unroll
        for (int a = 0; a < 4; ++a)
            af[a] = *(const bf16x8*)&cs[buf][quad][16 * a + l16][0];

#pragma unroll
        for (int jt = 0; jt < 6; ++jt) {
            int n = nb + 96 * w + 16 * jt + l16;
            const float* wp = W + (size_t)n * 768 + kc * 32 + quad * 8;
            float4 f0 = *(const float4*)(wp);
            float4 f1 = *(const float4*)(wp + 4);
            B8 wh, wl;
            split2(f0.x, wh.s[0], wl.s[0]); split2(f0.y, wh.s[1], wl.s[1]);
            split2(f0.z, wh.s[2], wl.s[2]); split2(f0.w, wh.s[3], wl.s[3]);
            split2(f1.x, wh.s[4], wl.s[4]); split2(f1.y, wh.s[5], wl.s[5]);
            split2(f1.z, wh.s[6], wl.s[6]); split2(f1.w, wh.s[7], wl.s[7]);
#pragma unroll
            for (int a = 0; a < 4; ++a) {
                acc[a][jt] = __builtin_amdgcn_mfma_f32_16x16x32_bf16(af[a], wh.v, acc[a][jt], 0, 0, 0);
                acc[a][jt] = __builtin_amdgcn_mfma_f32_16x16x32_bf16(af[a], wl.v, acc[a][jt], 0, 0, 0);
            }
        }
    }

    // C/D layout: col = lane&15, row = quad*4 + reg.
#pragma unroll
    for (int jt = 0; jt < 6; ++jt) {
        int n = nb + 96 * w + 16 * jt + l16;
        float bs = bias[n];
#pragma unroll
        for (int a = 0; a < 4; ++a) {
#pragma unroll
            for (int r = 0; r < 4; ++r) {
                int row = 16 * a + quad * 4 + r;
                out0[(size_t)(t0 + row) * 768 + n] = acc[a][jt][r] + bs;
            }
        }
    }
}

// ---------------------------------------------------------------------------
extern "C" void kernel_launch(void* const* d_in, const int* in_sizes, int n_in,
                              void* d_out, int out_size, void* d_ws, size_t ws_size,
                              hipStream_t stream) {
    const float* x    = (const float*)d_in[0];
    const int*   mask = (const int*)d_in[1];
    const float* wq = (const float*)d_in[2];
    const float* bq = (const float*)d_in[3];
    const float* wk = (const float*)d_in[4];
    const float* bk = (const float*)d_in[5];
    const float* wv = (const float*)d_in[6];
    const float* bv = (const float*)d_in[7];
    const float* wo = (const float*)d_in[8];
    const float* bo = (const float*)d_in[9];

    float* out0  = (float*)d_out;                // TE f32 (slot-interleaved scratch)
    u16*   slots = (u16*)d_out;                  // ctx even halves, V odd halves
    u16*   winU  = (u16*)(out0 + TE);            // probs region: windows -> probs

    // W fragment-chunk scratch in even halves of slots [0,6912) (dead until attn).
    convert_w3<<<dim3(288, 3), dim3(256), 0, stream>>>(wq, wk, wv, slots);
    // Fused Q,K,V projection (A staged once, coalesced B chunk reads).
    gemm_qkv<<<dim3(1536), dim3(512), 0, stream>>>(x, slots, bq, bk, bv, winU, slots);
    attn_kernel<<<dim3(12 * 256), dim3(256), 0, stream>>>(winU, slots, mask);
    // Order matters: cols [384,768) first (odd halves, dead V), then [0,384)
    // (even halves = each block's own, already-read ctx).
    gemm_out<<<dim3(512), dim3(256), 0, stream>>>(slots, wo, bo, out0, 384);
    gemm_out<<<dim3(512), dim3(256), 0, stream>>>(slots, wo, bo, out0, 0);
}